// Round 6
// baseline (340.953 us; speedup 1.0000x reference)
//
#include <hip/hip_runtime.h>
#include <hip/hip_bf16.h>
#include <cstdint>

#define D_MODEL 2048
#define D_REC   384
#define NPROJ   1152          // 3*D_REC
#define BATCH   4
#define SEQ     4096
#define M_TOTAL (BATCH*SEQ)   // 16384
#define CHUNK   64
#define NCHUNK  (SEQ/CHUNK)   // 64
#define LDP     65            // odd stride for cross_final tiles
#define LDSP    193           // odd stride for gemm epilogue Cs tile (192+1)

typedef __attribute__((ext_vector_type(8))) short  short8;
typedef __attribute__((ext_vector_type(4))) float  f32x4;

__device__ __forceinline__ float rcpf(float x) { return __builtin_amdgcn_rcpf(x); }

// ---------------------------------------------------------------- convert
// x -> xb (bf16, same layout). W -> Wb (bf16, ROWS REORDERED):
// original row n = p*384 + g*64 + dl  ->  new row n' = g*192 + p*64 + dl
// so an n-tile of 192 holds {a,i,v} for the same 64 d's.
__device__ __forceinline__ uint16_t f2bf(float x) {
    __hip_bfloat16 h = __float2bfloat16(x);
    return *reinterpret_cast<uint16_t*>(&h);
}

__global__ void cvt_both(const float* __restrict__ x, const float* __restrict__ W,
                         uint16_t* __restrict__ xb, uint16_t* __restrict__ Wb,
                         long nx, long nw) {
    long i = ((long)blockIdx.x * blockDim.x + threadIdx.x) * 4;
    float4 f;
    ushort4 o;
    if (i < nx) {
        f = *reinterpret_cast<const float4*>(x + i);
        o.x = f2bf(f.x); o.y = f2bf(f.y); o.z = f2bf(f.z); o.w = f2bf(f.w);
        *reinterpret_cast<ushort4*>(xb + i) = o;
    } else {
        long j = i - nx;
        if (j >= nw) return;
        f = *reinterpret_cast<const float4*>(W + j);
        o.x = f2bf(f.x); o.y = f2bf(f.y); o.z = f2bf(f.z); o.w = f2bf(f.w);
        const int n = (int)(j >> 11);          // row (0..1151)
        const int k = (int)(j & 2047);
        const int p  = n / D_REC;              // 0=a,1=i,2=v
        const int d  = n - p * D_REC;          // 0..383
        const int g  = d >> 6;
        const int dl = d & 63;
        const int nprime = g * 192 + p * 64 + dl;
        *reinterpret_cast<ushort4*>(Wb + (long)nprime * 2048 + k) = o;
    }
}

// ---------------------------------------------------------------- fused GEMM + gate + intra-chunk scan
// Tile M=128 (2 chunks) x N=192 ({a,i,v} x 64 d's), BK=64, 4 waves (2x2).
// K-loop identical structure to R5 (XOR-swizzled global_load_lds, 0 conflicts).
// Epilogue: per chunk-half, dump acc->LDS, gate, Kogge-Stone scan, store cumdec/cumw.
__device__ __forceinline__ void gload_lds16(const uint16_t* g, uint16_t* l) {
    __builtin_amdgcn_global_load_lds(
        (__attribute__((address_space(1))) void*)g,
        (__attribute__((address_space(3))) void*)l,
        16, 0, 0);
}

__launch_bounds__(256)
__global__ void gemm_scan(const uint16_t* __restrict__ A,   // xb [16384][2048]
                          const uint16_t* __restrict__ Bm,  // Wb reordered [1152][2048]
                          const float* __restrict__ bias,   // [384]
                          float* __restrict__ cumdec,       // [B][S][D]
                          float* __restrict__ cumw,         // [B][S][D]
                          float* __restrict__ ctd,          // [B*NCHUNK][D]
                          float* __restrict__ cfs)          // [B*NCHUNK][D]
{
    __shared__ __align__(16) char smem[64 * LDSP * 4];      // 49,408 B
    uint16_t* As = (uint16_t*)smem;                         // [128*64]  16,384 B
    uint16_t* Bs = (uint16_t*)(smem + 128 * 64 * 2);        // [192*64]  24,576 B
    float*    Cs = (float*)smem;                            // [64*LDSP] 49,408 B (epilogue)

    const int tid  = threadIdx.x;
    const int wave = tid >> 6;
    const int lane = tid & 63;
    const int m0 = blockIdx.x * 128;
    const int g  = blockIdx.y;           // d-group 0..5
    const int n0 = g * 192;
    const int wm = (wave >> 1) * 64;     // 0 or 64 (timestep half)
    const int wn = (wave & 1) * 96;

    const int q  = lane >> 4;
    const int lm = lane & 15;
    const int h  = lm & 7;
    const int r_l = lane >> 3;
    const int cg  = (lane & 7) ^ r_l;

    f32x4 acc[4][6];
#pragma unroll
    for (int i = 0; i < 4; ++i)
#pragma unroll
        for (int j = 0; j < 6; ++j) acc[i][j] = (f32x4){0.f, 0.f, 0.f, 0.f};

    const long arow = (long)(m0 + wave * 32 + r_l) * D_MODEL + cg * 8;
    const long brow = (long)(n0 + wave * 48 + r_l) * D_MODEL + cg * 8;

    for (int k0 = 0; k0 < D_MODEL; k0 += 64) {
#pragma unroll
        for (int jj = 0; jj < 4; ++jj)
            gload_lds16(A + arow + (long)jj * 8 * D_MODEL + k0, &As[(wave * 32 + jj * 8) * 64]);
#pragma unroll
        for (int jj = 0; jj < 6; ++jj)
            gload_lds16(Bm + brow + (long)jj * 8 * D_MODEL + k0, &Bs[(wave * 48 + jj * 8) * 64]);
        __syncthreads();

#pragma unroll
        for (int s = 0; s < 2; ++s) {
            short8 af[4], bfr[6];
#pragma unroll
            for (int mt = 0; mt < 4; ++mt)
                af[mt] = *reinterpret_cast<const short8*>(
                    &As[(wm + mt * 16 + lm) * 64 + (((s * 4 + q) ^ h) * 8)]);
#pragma unroll
            for (int nt = 0; nt < 6; ++nt)
                bfr[nt] = *reinterpret_cast<const short8*>(
                    &Bs[(wn + nt * 16 + lm) * 64 + (((s * 4 + q) ^ h) * 8)]);
#pragma unroll
            for (int mt = 0; mt < 4; ++mt)
#pragma unroll
                for (int nt = 0; nt < 6; ++nt)
                    acc[mt][nt] = __builtin_amdgcn_mfma_f32_16x16x32_bf16(af[mt], bfr[nt], acc[mt][nt], 0, 0, 0);
        }
        __syncthreads();
    }

    // ---------------- epilogue: two chunk-halves
    const int dd4 = (tid & 15) * 4;
#pragma unroll
    for (int half = 0; half < 2; ++half) {
        // dump this half's 64x192 fp32 tile into Cs[t][n'] (waves with wm==half*64)
        if ((wave >> 1) == half) {
#pragma unroll
            for (int mt = 0; mt < 4; ++mt)
#pragma unroll
                for (int nt = 0; nt < 6; ++nt)
#pragma unroll
                    for (int r = 0; r < 4; ++r)
                        Cs[(mt * 16 + q * 4 + r) * LDSP + wn + nt * 16 + lm] = acc[mt][nt][r];
        }
        __syncthreads();

        // gate + Kogge-Stone scan; lane = t, each wave does 16 d-lanes
#pragma unroll 4
        for (int p = 0; p < 16; ++p) {
            const int dl = p * 4 + wave;
            const float bias_v = bias[g * 64 + dl];
            const float araw = Cs[lane * LDSP + dl];
            const float iraw = Cs[lane * LDSP + 64 + dl];
            const float vraw = Cs[lane * LDSP + 128 + dl];

            const float a  = rcpf(1.f + __expf(-(araw + bias_v)));
            const float gg = rcpf(1.f + __expf(-iraw));
            const float sig = sqrtf(fmaxf(1.f - a * a, 1e-8f)) * (gg * vraw);

            float cd = fmaxf(a, 1e-10f);
#pragma unroll
            for (int off = 1; off < 64; off <<= 1) {
                const float o = __shfl_up(cd, off, 64);
                if (lane >= off) cd *= o;
            }
            float cw = sig * rcpf(fmaxf(cd, 1e-10f));
#pragma unroll
            for (int off = 1; off < 64; off <<= 1) {
                const float o = __shfl_up(cw, off, 64);
                if (lane >= off) cw += o;
            }
            Cs[lane * LDSP + dl]      = cd;
            Cs[lane * LDSP + 64 + dl] = cw;
        }
        __syncthreads();

        // store: coalesced float4
        const int chunkIdx = blockIdx.x * 2 + half;     // = b*64 + c
#pragma unroll
        for (int pp = 0; pp < 4; ++pp) {
            const int t = pp * 16 + (tid >> 4);
            const long row = ((long)chunkIdx * CHUNK + t) * D_REC + g * 64 + dd4;
            float4 cd4, cw4;
            cd4.x = Cs[t * LDSP + dd4 + 0]; cd4.y = Cs[t * LDSP + dd4 + 1];
            cd4.z = Cs[t * LDSP + dd4 + 2]; cd4.w = Cs[t * LDSP + dd4 + 3];
            cw4.x = Cs[t * LDSP + 64 + dd4 + 0]; cw4.y = Cs[t * LDSP + 64 + dd4 + 1];
            cw4.z = Cs[t * LDSP + 64 + dd4 + 2]; cw4.w = Cs[t * LDSP + 64 + dd4 + 3];
            *reinterpret_cast<float4*>(&cumdec[row]) = cd4;
            *reinterpret_cast<float4*>(&cumw[row])   = cw4;
            if (t == 63) {
                const long cb = (long)chunkIdx * D_REC + g * 64 + dd4;
                float4 fs4;
                fs4.x = cd4.x * cw4.x; fs4.y = cd4.y * cw4.y;
                fs4.z = cd4.z * cw4.z; fs4.w = cd4.w * cw4.w;
                *reinterpret_cast<float4*>(&ctd[cb]) = cd4;
                *reinterpret_cast<float4*>(&cfs[cb]) = fs4;
            }
        }
        __syncthreads();   // Cs reused by next half
    }
}

// ---------------------------------------------------------------- cross-scan + final-combine (unchanged from R5)
__global__ void cross_final(const float* __restrict__ ctd, const float* __restrict__ cfs,
                            const float* __restrict__ cumdec, const float* __restrict__ cumw,
                            float* __restrict__ out)
{
    __shared__ float Tb[64 * LDP];
    __shared__ float Fb[64 * LDP];

    const int tid  = threadIdx.x;
    const int wave = tid >> 6;
    const int lane = tid & 63;
    const int b  = blockIdx.x;
    const int D0 = blockIdx.y * 64;
    const int cz = blockIdx.z;

    const int dd4 = (tid & 15) * 4;

#pragma unroll
    for (int p = 0; p < 4; ++p) {
        const int cc = p * 16 + (tid >> 4);
        const long row = ((long)b * NCHUNK + cc) * D_REC + D0 + dd4;
        const float4 t4 = *reinterpret_cast<const float4*>(&ctd[row]);
        const float4 f4 = *reinterpret_cast<const float4*>(&cfs[row]);
#pragma unroll
        for (int j = 0; j < 4; ++j) {
            Tb[cc * LDP + dd4 + j] = (&t4.x)[j];
            Fb[cc * LDP + dd4 + j] = (&f4.x)[j];
        }
    }
    __syncthreads();

#pragma unroll 4
    for (int p = 0; p < 16; ++p) {
        const int dd = p * 4 + wave;
        const float td = Tb[lane * LDP + dd];
        const float fs = Fb[lane * LDP + dd];

        float cdk = fmaxf(td, 1e-10f);
#pragma unroll
        for (int off = 1; off < 64; off <<= 1) {
            const float o = __shfl_up(cdk, off, 64);
            if (lane >= off) cdk *= o;
        }
        float cwk = fs * rcpf(fmaxf(cdk, 1e-10f));
#pragma unroll
        for (int off = 1; off < 64; off <<= 1) {
            const float o = __shfl_up(cwk, off, 64);
            if (lane >= off) cwk += o;
        }
        const float st = cdk * cwk;
        float e = __shfl_up(st, 1, 64);
        if (lane == 0) e = 0.f;
        Tb[lane * LDP + dd] = e;
    }
    __syncthreads();

#pragma unroll
    for (int j = 0; j < 4; ++j) {
        const int c = cz * 4 + j;
        float4 ic;
        ic.x = Tb[c * LDP + dd4 + 0]; ic.y = Tb[c * LDP + dd4 + 1];
        ic.z = Tb[c * LDP + dd4 + 2]; ic.w = Tb[c * LDP + dd4 + 3];
#pragma unroll
        for (int r4 = 0; r4 < 4; ++r4) {
            const int t = r4 * 16 + (tid >> 4);
            const long row = ((long)b * SEQ + (long)c * CHUNK + t) * D_REC + D0 + dd4;
            const float4 cd4 = *reinterpret_cast<const float4*>(&cumdec[row]);
            const float4 cw4 = *reinterpret_cast<const float4*>(&cumw[row]);
            float4 o;
            o.x = cd4.x * (cw4.x + ic.x);
            o.y = cd4.y * (cw4.y + ic.y);
            o.z = cd4.z * (cw4.z + ic.z);
            o.w = cd4.w * (cw4.w + ic.w);
            *reinterpret_cast<float4*>(&out[row]) = o;
        }
    }
}

// ---------------------------------------------------------------- launch
extern "C" void kernel_launch(void* const* d_in, const int* in_sizes, int n_in,
                              void* d_out, int out_size, void* d_ws, size_t ws_size,
                              hipStream_t stream) {
    const float* x  = (const float*)d_in[0];   // [4][4096][2048]
    const float* W  = (const float*)d_in[1];   // [1152][2048]
    const float* db = (const float*)d_in[2];   // [384]
    float* out = (float*)d_out;                // [4][4096][384]

    char* ws = (char*)d_ws;
    uint16_t* xb     = (uint16_t*)(ws + 0);                 // 67,108,864 B
    uint16_t* Wb     = (uint16_t*)(ws + 67108864L);         //  4,718,592 B
    float*    cumdec = (float*)   (ws + 71827456L);         // 25,165,824 B
    float*    cumw   = (float*)   (ws + 96993280L);         // 25,165,824 B
    float*    ctd    = (float*)   (ws + 122159104L);        //    393,216 B
    float*    cfs    = (float*)   (ws + 122552320L);        //    393,216 B

    const long nx = (long)M_TOTAL * D_MODEL;   // 33,554,432
    const long nw = (long)NPROJ * D_MODEL;     //  2,359,296

    // 1. convert x + reorder-convert W (single launch)
    cvt_both<<<(int)((nx + nw) / (4 * 256)), 256, 0, stream>>>(x, W, xb, Wb, nx, nw);

    // 2. fused GEMM + gate + intra-chunk scan
    gemm_scan<<<dim3(M_TOTAL / 128, D_REC / 64), 256, 0, stream>>>(xb, Wb, db, cumdec, cumw, ctd, cfs);

    // 3. fused cross-chunk scan + combine
    cross_final<<<dim3(BATCH, 6, 16), 256, 0, stream>>>(ctd, cfs, cumdec, cumw, out);
}